// Round 5
// baseline (205.605 us; speedup 1.0000x reference)
//
#include <hip/hip_runtime.h>
#include <cstdint>

#define EPS 1e-5f

typedef unsigned long long u64;
typedef unsigned int u32;
typedef unsigned short u16;
typedef unsigned char u8;
typedef float v2f __attribute__((ext_vector_type(2)));

__device__ __forceinline__ int clampi(int v, int lo, int hi) {
    return v < lo ? lo : (v > hi ? hi : v);
}

// exact elementwise helpers (packed when HW/compiler support, scalar-exact fallback)
__device__ __forceinline__ v2f v2_fma(v2f a, v2f b, v2f c) {
#if __has_builtin(__builtin_elementwise_fma)
    return __builtin_elementwise_fma(a, b, c);
#else
    v2f r; r.x = __builtin_fmaf(a.x, b.x, c.x); r.y = __builtin_fmaf(a.y, b.y, c.y); return r;
#endif
}
__device__ __forceinline__ v2f v2_min(v2f a, v2f b) {
#if __has_builtin(__builtin_elementwise_min)
    return __builtin_elementwise_min(a, b);
#else
    v2f r; r.x = fminf(a.x, b.x); r.y = fminf(a.y, b.y); return r;
#endif
}
__device__ __forceinline__ v2f v2_max(v2f a, v2f b) {
#if __has_builtin(__builtin_elementwise_max)
    return __builtin_elementwise_max(a, b);
#else
    v2f r; r.x = fmaxf(a.x, b.x); r.y = fmaxf(a.y, b.y); return r;
#endif
}

// ======================= prep_tiny: small packing + bn folding (7 blocks) =======================

__global__ __launch_bounds__(256) void prep_tiny(
    const float* __restrict__ conv1_w, const float* __restrict__ conv2_w,
    const float* __restrict__ fc2_w,
    const float* __restrict__ g1, const float* __restrict__ b1,
    const float* __restrict__ m1, const float* __restrict__ v1,
    const float* __restrict__ g2, const float* __restrict__ b2,
    const float* __restrict__ m2, const float* __restrict__ v2,
    v2f* __restrict__ s1d, u64* __restrict__ w2p, u64* __restrict__ w2pk,
    float4* __restrict__ bnc1, float4* __restrict__ bnc2)
{
    int t = blockIdx.x * 256 + threadIdx.x;
    if (t < 576) {
        float s = (conv1_w[t] >= 0.f) ? 1.f : -1.f;
        v2f d; d.x = s; d.y = s;
        s1d[t] = d;                             // duplicated for v_pk_fma
    } else if (t < 1152) {
        int u = t - 576;
        int co = u / 9, tap = u % 9;
        u64 word = 0;
        for (int ci = 0; ci < 64; ci++)
            word |= (u64)(conv2_w[(co * 64 + ci) * 9 + tap] >= 0.f) << ci;
        w2p[u] = word;
    } else if (t < 1472) {
        int u = t - 1152;
        int o = u / 32, k = u % 32;
        u64 word = 0;
        for (int j = 0; j < 64; j++)
            word |= (u64)(fc2_w[o * 2048 + k * 64 + j] >= 0.f) << j;
        w2pk[u] = word;
    } else if (t < 1536) {
        int ch = t - 1472;
        bnc1[ch] = make_float4(m1[ch], g1[ch] / sqrtf(v1[ch] + EPS), b1[ch], 0.f);
    } else if (t < 1600) {
        int ch = t - 1536;
        bnc2[ch] = make_float4(m2[ch], g2[ch] / sqrtf(v2[ch] + EPS), b2[ch], 0.f);
    }
}

// ---------- K1+repack: one dispatch, two independent block roles ----------
// blocks [0,2048):    fc1-weight repack (25.7MB HBM fetch) — runs CONCURRENTLY
//                     with conv1 blocks; its output wp is consumed only by k_fc1,
//                     two dispatch boundaries later (visibility guaranteed).
// blocks [2048,8320): conv1 + bn1 + sign + maxpool, proven round-0 shape
//                     (16 ch/thread, 4 groups, 25088 waves) with pk-fp32 core.
// Repack bit-packing is wave-parallel: lane = channel c, ballot -> u64 word
// (identical bit order to the serial version; absmax must stay 0).

__global__ __launch_bounds__(256) void k_conv1r(
    const float* __restrict__ x, const v2f* __restrict__ s1d,
    const float4* __restrict__ bnc1, u64* __restrict__ out1,
    const float* __restrict__ fc1_w, u64* __restrict__ wp)
{
    __shared__ float ls[3136];
    int tid = threadIdx.x;
    int bid = blockIdx.x;

    if (bid < 2048) {
        // ---- repack role: fc1_w row o -> wp[p*2048+o], bit c ----
        int o = bid;
        const float4* row4 = (const float4*)(fc1_w + o * 3136);
        for (int i = tid; i < 784; i += 256)
            ((float4*)ls)[i] = row4[i];
        __syncthreads();
        int lane = tid & 63, wv = tid >> 6;
        for (int p = wv; p < 49; p += 4) {          // p wave-uniform
            float v = ls[lane * 49 + p];            // bank stride 17 -> conflict-free
            u64 ball = __ballot(v >= 0.f);          // bit c = lane c sign
            if (lane == 0) wp[p * 2048 + o] = ball;
        }
        return;
    }

    // ---- conv1 role ----
    int idx2 = bid - 2048;                     // 0..6271
    int g = idx2 & 3;                          // group fastest: neighbors share patch rows in L2
    int base = g * 16;
    int idx = (idx2 >> 2) * 256 + tid;         // b*196 + p, exactly 401408
    int b = idx / 196, p = idx % 196;
    int pi = p / 14, pj = p % 14;

    const float* xb = x + b * 784;
    int rr[4], cc[4];
    #pragma unroll
    for (int r = 0; r < 4; r++) rr[r] = clampi(2 * pi - 1 + r, 0, 27) * 28;
    #pragma unroll
    for (int c = 0; c < 4; c++) cc[c] = clampi(2 * pj - 1 + c, 0, 27);
    float patch[4][4];
    #pragma unroll
    for (int r = 0; r < 4; r++)
        #pragma unroll
        for (int c = 0; c < 4; c++)
            patch[r][c] = xb[rr[r] + cc[c]];

    // adjacent-column pairs, shared by all 16 channels
    v2f pp[4][3];
    #pragma unroll
    for (int r = 0; r < 4; r++)
        #pragma unroll
        for (int j = 0; j < 3; j++) {
            v2f t; t.x = patch[r][j]; t.y = patch[r][j + 1];
            pp[r][j] = t;
        }

    u32 word = 0;
    #pragma unroll 4
    for (int ch = 0; ch < 16; ch++) {
        const v2f* w = s1d + (base + ch) * 9;   // wave-uniform -> s_load_dwordx2
        v2f a01 = 0.f, a23 = 0.f;               // {v00,v01}, {v10,v11}
        #pragma unroll
        for (int ki = 0; ki < 3; ki++)
            #pragma unroll
            for (int kj = 0; kj < 3; kj++) {
                v2f ww = w[ki * 3 + kj];
                a01 = v2_fma(pp[ki][kj],     ww, a01);
                a23 = v2_fma(pp[ki + 1][kj], ww, a23);
            }
        v2f mn = v2_min(a01, a23);
        v2f mx = v2_max(a01, a23);
        float vmin = fminf(mn.x, mn.y);
        float vmax = fmaxf(mx.x, mx.y);
        float4 c4 = bnc1[base + ch];            // wave-uniform -> s_load_dwordx4
        int bit = (((vmin - c4.x) * c4.y + c4.z) >= 0.f) |
                  (((vmax - c4.x) * c4.y + c4.z) >= 0.f);
        word |= (u32)bit << ch;
    }
    ((u16*)out1)[idx * 4 + g] = (u16)word;      // little-endian u64 quarters
}

// ---------- K2: conv2 + bn2 + sign + maxpool -> packed [B,7,7] (unchanged, proven) ----------

__global__ __launch_bounds__(256) void k_conv2(
    const u64* __restrict__ in, const u64* __restrict__ w2p,
    const float4* __restrict__ bnc2, u64* __restrict__ out2)
{
    int tid = threadIdx.x;
    int g = blockIdx.y;
    int base = g * 8;

    int idx = blockIdx.x * 256 + tid;          // b*49 + p, exactly 100352
    int b = idx / 49, p = idx % 49;
    int pi = p / 7, pj = p % 7;

    const u64* ib = in + b * 196;
    int rr[4], cc[4];
    #pragma unroll
    for (int r = 0; r < 4; r++) rr[r] = clampi(2 * pi - 1 + r, 0, 13) * 14;
    #pragma unroll
    for (int c = 0; c < 4; c++) cc[c] = clampi(2 * pj - 1 + c, 0, 13);
    u64 a[4][4];
    #pragma unroll
    for (int r = 0; r < 4; r++)
        #pragma unroll
        for (int c = 0; c < 4; c++)
            a[r][c] = ib[rr[r] + cc[c]];

    u32 word = 0;
    #pragma unroll
    for (int co = 0; co < 8; co++) {
        const u64* w = w2p + (base + co) * 9;   // wave-uniform -> s_load
        int s00 = 0, s01 = 0, s10 = 0, s11 = 0;
        #pragma unroll
        for (int ki = 0; ki < 3; ki++)
            #pragma unroll
            for (int kj = 0; kj < 3; kj++) {
                u64 ww = w[ki * 3 + kj];
                s00 += __popcll(a[ki][kj] ^ ww);
                s01 += __popcll(a[ki][kj + 1] ^ ww);
                s10 += __popcll(a[ki + 1][kj] ^ ww);
                s11 += __popcll(a[ki + 1][kj + 1] ^ ww);
            }
        int smin = min(min(s00, s01), min(s10, s11));
        int smax = max(max(s00, s01), max(s10, s11));
        float4 c4 = bnc2[base + co];
        int bit = (((float)(576 - 2 * smin) - c4.x) * c4.y + c4.z >= 0.f) |
                  (((float)(576 - 2 * smax) - c4.x) * c4.y + c4.z >= 0.f);
        word |= (u32)bit << co;
    }
    ((u8*)out2)[idx * 8 + g] = (u8)word;        // little-endian u64 bytes
}

// ---------- K3: fc1 + bn3 + sign -> packed [B,32] (unchanged, proven) ----------

#define NB 8

__global__ __launch_bounds__(256) void k_fc1(
    const u64* __restrict__ act, const u64* __restrict__ wp,
    const float* __restrict__ g, const float* __restrict__ bt,
    const float* __restrict__ mn, const float* __restrict__ vr,
    u64* __restrict__ out3)
{
    int tid = threadIdx.x;
    int btile = blockIdx.x >> 3;               // 256 tiles of NB batches
    int otile = blockIdx.x & 7;                // 8 tiles of 256 outputs
    int b0 = btile * NB;
    int o = otile * 256 + tid;
    const u64* ab = act + b0 * 49;

    int sums[NB];
    #pragma unroll
    for (int i = 0; i < NB; i++) sums[i] = 0;

    for (int p = 0; p < 49; p++) {
        u64 w = wp[p * 2048 + o];
        #pragma unroll
        for (int bb = 0; bb < NB; bb++)
            sums[bb] += __popcll(ab[bb * 49 + p] ^ w);   // ab idx uniform -> s_load
    }

    float iv = g[o] / sqrtf(vr[o] + EPS);
    float m = mn[o], be = bt[o];
    #pragma unroll
    for (int bb = 0; bb < NB; bb++) {
        float y = ((float)(3136 - 2 * sums[bb]) - m) * iv + be;
        u64 ball = __ballot(y >= 0.f);
        if ((tid & 63) == 0) out3[(b0 + bb) * 32 + (o >> 6)] = ball;
    }
}

// ---------- K4: fc2 + scale (unchanged, proven) ----------

__global__ void k_fc2(const u64* __restrict__ act, const u64* __restrict__ w2,
                      const float* __restrict__ scale, float* __restrict__ out)
{
    int idx = blockIdx.x * 256 + threadIdx.x;  // b*16 + o (o<10 active)
    if (idx >= 2048 * 16) return;
    int b = idx >> 4, o = idx & 15;
    if (o >= 10) return;
    int s = 0;
    #pragma unroll
    for (int k = 0; k < 32; k++)
        s += __popcll(act[b * 32 + k] ^ w2[o * 32 + k]);
    out[b * 10 + o] = scale[0] * (float)(2048 - 2 * s);
}

// ======================= launch =======================

extern "C" void kernel_launch(void* const* d_in, const int* in_sizes, int n_in,
                              void* d_out, int out_size, void* d_ws, size_t ws_size,
                              hipStream_t stream) {
    const float* x        = (const float*)d_in[0];
    const float* conv1_w  = (const float*)d_in[1];
    const float* bn1_g    = (const float*)d_in[2];
    const float* bn1_b    = (const float*)d_in[3];
    const float* bn1_m    = (const float*)d_in[4];
    const float* bn1_v    = (const float*)d_in[5];
    const float* conv2_w  = (const float*)d_in[6];
    const float* bn2_g    = (const float*)d_in[7];
    const float* bn2_b    = (const float*)d_in[8];
    const float* bn2_m    = (const float*)d_in[9];
    const float* bn2_v    = (const float*)d_in[10];
    const float* fc1_w    = (const float*)d_in[11];
    const float* bn3_g    = (const float*)d_in[12];
    const float* bn3_b    = (const float*)d_in[13];
    const float* bn3_m    = (const float*)d_in[14];
    const float* bn3_v    = (const float*)d_in[15];
    const float* fc2_w    = (const float*)d_in[16];
    const float* scale    = (const float*)d_in[17];
    float* out = (float*)d_out;

    char* ws = (char*)d_ws;
    v2f*    s1d  = (v2f*)   (ws + 0);          //   4608 B (ends 4608)
    u64*    w2p  = (u64*)   (ws + 4608);       //   4608 B (ends 9216)
    float4* bnc1 = (float4*)(ws + 9216);       //   1024 B (ends 10240)
    float4* bnc2 = (float4*)(ws + 10240);      //   1024 B (ends 11264)
    u64*    w2pk = (u64*)   (ws + 11264);      //   2560 B (ends 13824)
    u64*    wp   = (u64*)   (ws + 16384);      // 802816 B (ends 819200)
    u64*    out1 = (u64*)   (ws + 819200);     // 3211264 B (ends 4030464)
    u64*    out2 = (u64*)   (ws + 4030464);    // 802816 B (ends 4833280)
    u64*    out3 = (u64*)   (ws + 4833280);    // 524288 B (ends 5357568)

    hipLaunchKernelGGL(prep_tiny, dim3(7), dim3(256), 0, stream,
                       conv1_w, conv2_w, fc2_w,
                       bn1_g, bn1_b, bn1_m, bn1_v,
                       bn2_g, bn2_b, bn2_m, bn2_v,
                       s1d, w2p, w2pk, bnc1, bnc2);

    // repack blocks first (start the 25.7MB HBM stream), conv1 blocks follow
    hipLaunchKernelGGL(k_conv1r, dim3(2048 + 6272), dim3(256), 0, stream,
                       x, s1d, bnc1, out1, fc1_w, wp);
    hipLaunchKernelGGL(k_conv2, dim3(392, 8), dim3(256), 0, stream,
                       out1, w2p, bnc2, out2);
    hipLaunchKernelGGL(k_fc1, dim3(2048), dim3(256), 0, stream,
                       out2, wp, bn3_g, bn3_b, bn3_m, bn3_v, out3);
    hipLaunchKernelGGL(k_fc2, dim3(128), dim3(256), 0, stream,
                       out3, w2pk, scale, out);
}

// Round 6
// 204.913 us; speedup vs baseline: 1.0034x; 1.0034x over previous
//
#include <hip/hip_runtime.h>
#include <cstdint>

#define EPS 1e-5f

typedef unsigned long long u64;
typedef unsigned int u32;
typedef unsigned short u16;
typedef unsigned char u8;
typedef float v2f __attribute__((ext_vector_type(2)));

__device__ __forceinline__ int clampi(int v, int lo, int hi) {
    return v < lo ? lo : (v > hi ? hi : v);
}

// exact elementwise helpers (packed when HW/compiler support, scalar-exact fallback)
__device__ __forceinline__ v2f v2_fma(v2f a, v2f b, v2f c) {
#if __has_builtin(__builtin_elementwise_fma)
    return __builtin_elementwise_fma(a, b, c);
#else
    v2f r; r.x = __builtin_fmaf(a.x, b.x, c.x); r.y = __builtin_fmaf(a.y, b.y, c.y); return r;
#endif
}
__device__ __forceinline__ v2f v2_max(v2f a, v2f b) {
#if __has_builtin(__builtin_elementwise_max)
    return __builtin_elementwise_max(a, b);
#else
    v2f r; r.x = fmaxf(a.x, b.x); r.y = fmaxf(a.y, b.y); return r;
#endif
}

// ---------- K1: one dispatch, three independent block roles ----------
// blocks [0,2048):      fc1-weight repack (25.7MB HBM fetch), output wp consumed
//                       only by k_fc1 (2 dispatch boundaries later) -> safe.
// blocks [2048,2055):   tiny prep (w2p/w2pk/bnc2 for conv2/fc2 dispatches) -> safe.
//                       (also writes s1d/bnc1; now unused downstream, kept verbatim)
// blocks [2055,8327):   conv1 + bn1 + sign + maxpool, proven 16-ch/thread shape.
//                       Self-sufficient: computes its own ±1 weights + bn consts
//                       into LDS (same formulas -> same bits as prep did).
// conv1 epilogue: bn is monotone nondecreasing (iv=gamma/sqrt(var+eps) >= 0, RN
// rounding is monotone) -> y(vmin) <= y(vmax) exactly -> only the vmax path
// decides the bit. Survivor expression verbatim -> bit-exact vs baseline.

__global__ __launch_bounds__(256) void k_conv1r(
    const float* __restrict__ x,
    const float* __restrict__ conv1_w, const float* __restrict__ conv2_w,
    const float* __restrict__ fc2_w,
    const float* __restrict__ g1, const float* __restrict__ b1,
    const float* __restrict__ m1, const float* __restrict__ v1,
    const float* __restrict__ g2, const float* __restrict__ b2,
    const float* __restrict__ m2, const float* __restrict__ v2,
    v2f* __restrict__ s1d, u64* __restrict__ w2p, u64* __restrict__ w2pk,
    float4* __restrict__ bnc1, float4* __restrict__ bnc2,
    u64* __restrict__ out1,
    const float* __restrict__ fc1_w, u64* __restrict__ wp)
{
    __shared__ float ls[3136];
    int tid = threadIdx.x;
    int bid = blockIdx.x;

    if (bid < 2048) {
        // ---- repack role: fc1_w row o -> wp[p*2048+o], bit c ----
        int o = bid;
        const float4* row4 = (const float4*)(fc1_w + o * 3136);
        for (int i = tid; i < 784; i += 256)
            ((float4*)ls)[i] = row4[i];
        __syncthreads();
        int lane = tid & 63, wv = tid >> 6;
        for (int p = wv; p < 49; p += 4) {          // p wave-uniform
            float v = ls[lane * 49 + p];            // bank stride 17 -> conflict-free
            u64 ball = __ballot(v >= 0.f);          // bit c = lane c sign
            if (lane == 0) wp[p * 2048 + o] = ball;
        }
        return;
    }

    if (bid < 2055) {
        // ---- tiny-prep role (verbatim from prep_tiny) ----
        int t = (bid - 2048) * 256 + tid;
        if (t < 576) {
            float s = (conv1_w[t] >= 0.f) ? 1.f : -1.f;
            v2f d; d.x = s; d.y = s;
            s1d[t] = d;
        } else if (t < 1152) {
            int u = t - 576;
            int co = u / 9, tap = u % 9;
            u64 word = 0;
            for (int ci = 0; ci < 64; ci++)
                word |= (u64)(conv2_w[(co * 64 + ci) * 9 + tap] >= 0.f) << ci;
            w2p[u] = word;
        } else if (t < 1472) {
            int u = t - 1152;
            int o = u / 32, k = u % 32;
            u64 word = 0;
            for (int j = 0; j < 64; j++)
                word |= (u64)(fc2_w[o * 2048 + k * 64 + j] >= 0.f) << j;
            w2pk[u] = word;
        } else if (t < 1536) {
            int ch = t - 1472;
            bnc1[ch] = make_float4(m1[ch], g1[ch] / sqrtf(v1[ch] + EPS), b1[ch], 0.f);
        } else if (t < 1600) {
            int ch = t - 1536;
            bnc2[ch] = make_float4(m2[ch], g2[ch] / sqrtf(v2[ch] + EPS), b2[ch], 0.f);
        }
        return;
    }

    // ---- conv1 role ----
    int idx2 = bid - 2055;                     // 0..6271
    int g = idx2 & 3;                          // group fastest: L2 locality on x
    int base = g * 16;

    // self-compute this group's ±1 weights (duplicated for pk_fma) + bn consts
    v2f*    lw = (v2f*)ls;                     // 144 v2f  (1152 B)
    float4* lb = (float4*)(ls + 288);          // 16 float4 (16B-aligned: 288*4=1152)
    if (tid < 144) {
        float f = conv1_w[g * 144 + tid];      // group slice is contiguous
        float s = (f >= 0.f) ? 1.f : -1.f;
        v2f d; d.x = s; d.y = s;
        lw[tid] = d;
    } else if (tid < 160) {
        int ch = base + (tid - 144);
        lb[tid - 144] = make_float4(m1[ch], g1[ch] / sqrtf(v1[ch] + EPS), b1[ch], 0.f);
    }
    __syncthreads();

    int idx = (idx2 >> 2) * 256 + tid;         // b*196 + p, exactly 401408
    int b = idx / 196, p = idx % 196;
    int pi = p / 14, pj = p % 14;

    const float* xb = x + b * 784;
    int rr[4], cc[4];
    #pragma unroll
    for (int r = 0; r < 4; r++) rr[r] = clampi(2 * pi - 1 + r, 0, 27) * 28;
    #pragma unroll
    for (int c = 0; c < 4; c++) cc[c] = clampi(2 * pj - 1 + c, 0, 27);
    float patch[4][4];
    #pragma unroll
    for (int r = 0; r < 4; r++)
        #pragma unroll
        for (int c = 0; c < 4; c++)
            patch[r][c] = xb[rr[r] + cc[c]];

    // adjacent-column pairs, shared by all 16 channels
    v2f pp[4][3];
    #pragma unroll
    for (int r = 0; r < 4; r++)
        #pragma unroll
        for (int j = 0; j < 3; j++) {
            v2f t; t.x = patch[r][j]; t.y = patch[r][j + 1];
            pp[r][j] = t;
        }

    u32 word = 0;
    #pragma unroll 4
    for (int ch = 0; ch < 16; ch++) {
        const v2f* w = lw + ch * 9;             // wave-uniform -> LDS broadcast
        v2f a01 = 0.f, a23 = 0.f;               // {v00,v01}, {v10,v11}
        #pragma unroll
        for (int ki = 0; ki < 3; ki++)
            #pragma unroll
            for (int kj = 0; kj < 3; kj++) {
                v2f ww = w[ki * 3 + kj];
                a01 = v2_fma(pp[ki][kj],     ww, a01);
                a23 = v2_fma(pp[ki + 1][kj], ww, a23);
            }
        v2f mx = v2_max(a01, a23);
        float vmax = fmaxf(mx.x, mx.y);
        float4 c4 = lb[ch];                     // wave-uniform -> LDS broadcast
        int bit = (((vmax - c4.x) * c4.y + c4.z) >= 0.f);   // vmin path dropped (monotone, exact)
        word |= (u32)bit << ch;
    }
    ((u16*)out1)[idx * 4 + g] = (u16)word;      // little-endian u64 quarters
}

// ---------- K2: conv2 + bn2 + sign + maxpool -> packed [B,7,7] ----------
// Proven grid (392,8). smax path dropped: y increasing in (576-2s), iv2 >= 0,
// RN monotone -> only smin decides the bit. Survivor expression verbatim.

__global__ __launch_bounds__(256) void k_conv2(
    const u64* __restrict__ in, const u64* __restrict__ w2p,
    const float4* __restrict__ bnc2, u64* __restrict__ out2)
{
    int tid = threadIdx.x;
    int g = blockIdx.y;
    int base = g * 8;

    int idx = blockIdx.x * 256 + tid;          // b*49 + p, exactly 100352
    int b = idx / 49, p = idx % 49;
    int pi = p / 7, pj = p % 7;

    const u64* ib = in + b * 196;
    int rr[4], cc[4];
    #pragma unroll
    for (int r = 0; r < 4; r++) rr[r] = clampi(2 * pi - 1 + r, 0, 13) * 14;
    #pragma unroll
    for (int c = 0; c < 4; c++) cc[c] = clampi(2 * pj - 1 + c, 0, 13);
    u64 a[4][4];
    #pragma unroll
    for (int r = 0; r < 4; r++)
        #pragma unroll
        for (int c = 0; c < 4; c++)
            a[r][c] = ib[rr[r] + cc[c]];

    u32 word = 0;
    #pragma unroll
    for (int co = 0; co < 8; co++) {
        const u64* w = w2p + (base + co) * 9;   // wave-uniform -> s_load
        int s00 = 0, s01 = 0, s10 = 0, s11 = 0;
        #pragma unroll
        for (int ki = 0; ki < 3; ki++)
            #pragma unroll
            for (int kj = 0; kj < 3; kj++) {
                u64 ww = w[ki * 3 + kj];
                s00 += __popcll(a[ki][kj] ^ ww);
                s01 += __popcll(a[ki][kj + 1] ^ ww);
                s10 += __popcll(a[ki + 1][kj] ^ ww);
                s11 += __popcll(a[ki + 1][kj + 1] ^ ww);
            }
        int smin = min(min(s00, s01), min(s10, s11));
        float4 c4 = bnc2[base + co];
        int bit = (((float)(576 - 2 * smin) - c4.x) * c4.y + c4.z >= 0.f);  // smax path dropped
        word |= (u32)bit << co;
    }
    ((u8*)out2)[idx * 8 + g] = (u8)word;        // little-endian u64 bytes
}

// ---------- K3: fc1 + bn3 + sign -> packed [B,32] (unchanged, proven) ----------

#define NB 8

__global__ __launch_bounds__(256) void k_fc1(
    const u64* __restrict__ act, const u64* __restrict__ wp,
    const float* __restrict__ g, const float* __restrict__ bt,
    const float* __restrict__ mn, const float* __restrict__ vr,
    u64* __restrict__ out3)
{
    int tid = threadIdx.x;
    int btile = blockIdx.x >> 3;               // 256 tiles of NB batches
    int otile = blockIdx.x & 7;                // 8 tiles of 256 outputs
    int b0 = btile * NB;
    int o = otile * 256 + tid;
    const u64* ab = act + b0 * 49;

    int sums[NB];
    #pragma unroll
    for (int i = 0; i < NB; i++) sums[i] = 0;

    for (int p = 0; p < 49; p++) {
        u64 w = wp[p * 2048 + o];
        #pragma unroll
        for (int bb = 0; bb < NB; bb++)
            sums[bb] += __popcll(ab[bb * 49 + p] ^ w);   // ab idx uniform -> s_load
    }

    float iv = g[o] / sqrtf(vr[o] + EPS);
    float m = mn[o], be = bt[o];
    #pragma unroll
    for (int bb = 0; bb < NB; bb++) {
        float y = ((float)(3136 - 2 * sums[bb]) - m) * iv + be;
        u64 ball = __ballot(y >= 0.f);
        if ((tid & 63) == 0) out3[(b0 + bb) * 32 + (o >> 6)] = ball;
    }
}

// ---------- K4: fc2 + scale (unchanged, proven) ----------

__global__ void k_fc2(const u64* __restrict__ act, const u64* __restrict__ w2,
                      const float* __restrict__ scale, float* __restrict__ out)
{
    int idx = blockIdx.x * 256 + threadIdx.x;  // b*16 + o (o<10 active)
    if (idx >= 2048 * 16) return;
    int b = idx >> 4, o = idx & 15;
    if (o >= 10) return;
    int s = 0;
    #pragma unroll
    for (int k = 0; k < 32; k++)
        s += __popcll(act[b * 32 + k] ^ w2[o * 32 + k]);
    out[b * 10 + o] = scale[0] * (float)(2048 - 2 * s);
}

// ======================= launch =======================

extern "C" void kernel_launch(void* const* d_in, const int* in_sizes, int n_in,
                              void* d_out, int out_size, void* d_ws, size_t ws_size,
                              hipStream_t stream) {
    const float* x        = (const float*)d_in[0];
    const float* conv1_w  = (const float*)d_in[1];
    const float* bn1_g    = (const float*)d_in[2];
    const float* bn1_b    = (const float*)d_in[3];
    const float* bn1_m    = (const float*)d_in[4];
    const float* bn1_v    = (const float*)d_in[5];
    const float* conv2_w  = (const float*)d_in[6];
    const float* bn2_g    = (const float*)d_in[7];
    const float* bn2_b    = (const float*)d_in[8];
    const float* bn2_m    = (const float*)d_in[9];
    const float* bn2_v    = (const float*)d_in[10];
    const float* fc1_w    = (const float*)d_in[11];
    const float* bn3_g    = (const float*)d_in[12];
    const float* bn3_b    = (const float*)d_in[13];
    const float* bn3_m    = (const float*)d_in[14];
    const float* bn3_v    = (const float*)d_in[15];
    const float* fc2_w    = (const float*)d_in[16];
    const float* scale    = (const float*)d_in[17];
    float* out = (float*)d_out;

    char* ws = (char*)d_ws;
    v2f*    s1d  = (v2f*)   (ws + 0);          //   4608 B (ends 4608)
    u64*    w2p  = (u64*)   (ws + 4608);       //   4608 B (ends 9216)
    float4* bnc1 = (float4*)(ws + 9216);       //   1024 B (ends 10240)
    float4* bnc2 = (float4*)(ws + 10240);      //   1024 B (ends 11264)
    u64*    w2pk = (u64*)   (ws + 11264);      //   2560 B (ends 13824)
    u64*    wp   = (u64*)   (ws + 16384);      // 802816 B (ends 819200)
    u64*    out1 = (u64*)   (ws + 819200);     // 3211264 B (ends 4030464)
    u64*    out2 = (u64*)   (ws + 4030464);    // 802816 B (ends 4833280)
    u64*    out3 = (u64*)   (ws + 4833280);    // 524288 B (ends 5357568)

    // repack + prep role blocks first (start the HBM streams), conv1 blocks follow
    hipLaunchKernelGGL(k_conv1r, dim3(2048 + 7 + 6272), dim3(256), 0, stream,
                       x, conv1_w, conv2_w, fc2_w,
                       bn1_g, bn1_b, bn1_m, bn1_v,
                       bn2_g, bn2_b, bn2_m, bn2_v,
                       s1d, w2p, w2pk, bnc1, bnc2,
                       out1, fc1_w, wp);
    hipLaunchKernelGGL(k_conv2, dim3(392, 8), dim3(256), 0, stream,
                       out1, w2p, bnc2, out2);
    hipLaunchKernelGGL(k_fc1, dim3(2048), dim3(256), 0, stream,
                       out2, wp, bn3_g, bn3_b, bn3_m, bn3_v, out3);
    hipLaunchKernelGGL(k_fc2, dim3(128), dim3(256), 0, stream,
                       out3, w2pk, scale, out);
}

// Round 7
// 200.296 us; speedup vs baseline: 1.0265x; 1.0231x over previous
//
#include <hip/hip_runtime.h>
#include <cstdint>

#define EPS 1e-5f

typedef unsigned long long u64;
typedef unsigned int u32;
typedef unsigned short u16;
typedef unsigned char u8;
typedef float v2f __attribute__((ext_vector_type(2)));

__device__ __forceinline__ int clampi(int v, int lo, int hi) {
    return v < lo ? lo : (v > hi ? hi : v);
}

// exact elementwise helpers (packed when HW/compiler support, scalar-exact fallback)
__device__ __forceinline__ v2f v2_fma(v2f a, v2f b, v2f c) {
#if __has_builtin(__builtin_elementwise_fma)
    return __builtin_elementwise_fma(a, b, c);
#else
    v2f r; r.x = __builtin_fmaf(a.x, b.x, c.x); r.y = __builtin_fmaf(a.y, b.y, c.y); return r;
#endif
}
__device__ __forceinline__ v2f v2_max(v2f a, v2f b) {
#if __has_builtin(__builtin_elementwise_max)
    return __builtin_elementwise_max(a, b);
#else
    v2f r; r.x = fmaxf(a.x, b.x); r.y = fmaxf(a.y, b.y); return r;
#endif
}

// ---------- K1: one dispatch, three independent block roles ----------
// blocks [0,2048):      fc1-weight repack (25.7MB HBM fetch), output wp consumed
//                       only by k_fc1 (2 dispatch boundaries later) -> safe.
// blocks [2048,2055):   tiny prep (w2p/w2pk/bnc2 for conv2/fc2 dispatches) -> safe.
// blocks [2055,8327):   conv1 + bn1 + sign + maxpool, 16 ch/thread, FULL channel
//                       unroll (VGPR 24 -> headroom; deepens pk_fma ILP to fix
//                       the measured 46% VALUBusy).
// conv1 epilogue: bn monotone nondecreasing -> only vmax path decides the bit
// (exact, survivor expression verbatim).

__global__ __launch_bounds__(256) void k_conv1r(
    const float* __restrict__ x,
    const float* __restrict__ conv1_w, const float* __restrict__ conv2_w,
    const float* __restrict__ fc2_w,
    const float* __restrict__ g1, const float* __restrict__ b1,
    const float* __restrict__ m1, const float* __restrict__ v1,
    const float* __restrict__ g2, const float* __restrict__ b2,
    const float* __restrict__ m2, const float* __restrict__ v2,
    v2f* __restrict__ s1d, u64* __restrict__ w2p, u64* __restrict__ w2pk,
    float4* __restrict__ bnc1, float4* __restrict__ bnc2,
    u64* __restrict__ out1,
    const float* __restrict__ fc1_w, u64* __restrict__ wp)
{
    __shared__ float ls[3136];
    int tid = threadIdx.x;
    int bid = blockIdx.x;

    if (bid < 2048) {
        // ---- repack role: fc1_w row o -> wp[p*2048+o], bit c ----
        int o = bid;
        const float4* row4 = (const float4*)(fc1_w + o * 3136);
        for (int i = tid; i < 784; i += 256)
            ((float4*)ls)[i] = row4[i];
        __syncthreads();
        int lane = tid & 63, wv = tid >> 6;
        for (int p = wv; p < 49; p += 4) {          // p wave-uniform
            float v = ls[lane * 49 + p];            // bank stride 17 -> conflict-free
            u64 ball = __ballot(v >= 0.f);          // bit c = lane c sign
            if (lane == 0) wp[p * 2048 + o] = ball;
        }
        return;
    }

    if (bid < 2055) {
        // ---- tiny-prep role ----
        int t = (bid - 2048) * 256 + tid;
        if (t < 576) {
            float s = (conv1_w[t] >= 0.f) ? 1.f : -1.f;
            v2f d; d.x = s; d.y = s;
            s1d[t] = d;
        } else if (t < 1152) {
            int u = t - 576;
            int co = u / 9, tap = u % 9;
            u64 word = 0;
            for (int ci = 0; ci < 64; ci++)
                word |= (u64)(conv2_w[(co * 64 + ci) * 9 + tap] >= 0.f) << ci;
            w2p[u] = word;
        } else if (t < 1472) {
            int u = t - 1152;
            int o = u / 32, k = u % 32;
            u64 word = 0;
            for (int j = 0; j < 64; j++)
                word |= (u64)(fc2_w[o * 2048 + k * 64 + j] >= 0.f) << j;
            w2pk[u] = word;
        } else if (t < 1536) {
            int ch = t - 1472;
            bnc1[ch] = make_float4(m1[ch], g1[ch] / sqrtf(v1[ch] + EPS), b1[ch], 0.f);
        } else if (t < 1600) {
            int ch = t - 1536;
            bnc2[ch] = make_float4(m2[ch], g2[ch] / sqrtf(v2[ch] + EPS), b2[ch], 0.f);
        }
        return;
    }

    // ---- conv1 role ----
    int idx2 = bid - 2055;                     // 0..6271
    int g = idx2 & 3;                          // group fastest: L2 locality on x
    int base = g * 16;

    // self-compute this group's ±1 weights (duplicated for pk_fma) + bn consts
    v2f*    lw = (v2f*)ls;                     // 144 v2f  (1152 B)
    float4* lb = (float4*)(ls + 288);          // 16 float4 (16B-aligned: 288*4=1152)
    if (tid < 144) {
        float f = conv1_w[g * 144 + tid];      // group slice is contiguous
        float s = (f >= 0.f) ? 1.f : -1.f;
        v2f d; d.x = s; d.y = s;
        lw[tid] = d;
    } else if (tid < 160) {
        int ch = base + (tid - 144);
        lb[tid - 144] = make_float4(m1[ch], g1[ch] / sqrtf(v1[ch] + EPS), b1[ch], 0.f);
    }
    __syncthreads();

    int idx = (idx2 >> 2) * 256 + tid;         // b*196 + p, exactly 401408
    int b = idx / 196, p = idx % 196;
    int pi = p / 14, pj = p % 14;

    const float* xb = x + b * 784;
    int rr[4], cc[4];
    #pragma unroll
    for (int r = 0; r < 4; r++) rr[r] = clampi(2 * pi - 1 + r, 0, 27) * 28;
    #pragma unroll
    for (int c = 0; c < 4; c++) cc[c] = clampi(2 * pj - 1 + c, 0, 27);
    float patch[4][4];
    #pragma unroll
    for (int r = 0; r < 4; r++)
        #pragma unroll
        for (int c = 0; c < 4; c++)
            patch[r][c] = xb[rr[r] + cc[c]];

    // adjacent-column pairs, shared by all 16 channels
    v2f pp[4][3];
    #pragma unroll
    for (int r = 0; r < 4; r++)
        #pragma unroll
        for (int j = 0; j < 3; j++) {
            v2f t; t.x = patch[r][j]; t.y = patch[r][j + 1];
            pp[r][j] = t;
        }

    u32 word = 0;
    #pragma unroll                              // FULL unroll: 144 LDS reads + 288 pk_fma in flight
    for (int ch = 0; ch < 16; ch++) {
        const v2f* w = lw + ch * 9;             // wave-uniform -> LDS broadcast
        v2f a01 = 0.f, a23 = 0.f;               // {v00,v01}, {v10,v11}
        #pragma unroll
        for (int ki = 0; ki < 3; ki++)
            #pragma unroll
            for (int kj = 0; kj < 3; kj++) {
                v2f ww = w[ki * 3 + kj];
                a01 = v2_fma(pp[ki][kj],     ww, a01);
                a23 = v2_fma(pp[ki + 1][kj], ww, a23);
            }
        v2f mx = v2_max(a01, a23);
        float vmax = fmaxf(mx.x, mx.y);
        float4 c4 = lb[ch];                     // wave-uniform -> LDS broadcast
        int bit = (((vmax - c4.x) * c4.y + c4.z) >= 0.f);   // vmin path dropped (monotone, exact)
        word |= (u32)bit << ch;
    }
    ((u16*)out1)[idx * 4 + g] = (u16)word;      // little-endian u64 quarters
}

// ---------- K2: conv2 + bn2 + sign + maxpool -> packed [B,7,7] (unchanged) ----------

__global__ __launch_bounds__(256) void k_conv2(
    const u64* __restrict__ in, const u64* __restrict__ w2p,
    const float4* __restrict__ bnc2, u64* __restrict__ out2)
{
    int tid = threadIdx.x;
    int g = blockIdx.y;
    int base = g * 8;

    int idx = blockIdx.x * 256 + tid;          // b*49 + p, exactly 100352
    int b = idx / 49, p = idx % 49;
    int pi = p / 7, pj = p % 7;

    const u64* ib = in + b * 196;
    int rr[4], cc[4];
    #pragma unroll
    for (int r = 0; r < 4; r++) rr[r] = clampi(2 * pi - 1 + r, 0, 13) * 14;
    #pragma unroll
    for (int c = 0; c < 4; c++) cc[c] = clampi(2 * pj - 1 + c, 0, 13);
    u64 a[4][4];
    #pragma unroll
    for (int r = 0; r < 4; r++)
        #pragma unroll
        for (int c = 0; c < 4; c++)
            a[r][c] = ib[rr[r] + cc[c]];

    u32 word = 0;
    #pragma unroll
    for (int co = 0; co < 8; co++) {
        const u64* w = w2p + (base + co) * 9;   // wave-uniform -> s_load
        int s00 = 0, s01 = 0, s10 = 0, s11 = 0;
        #pragma unroll
        for (int ki = 0; ki < 3; ki++)
            #pragma unroll
            for (int kj = 0; kj < 3; kj++) {
                u64 ww = w[ki * 3 + kj];
                s00 += __popcll(a[ki][kj] ^ ww);
                s01 += __popcll(a[ki][kj + 1] ^ ww);
                s10 += __popcll(a[ki + 1][kj] ^ ww);
                s11 += __popcll(a[ki + 1][kj + 1] ^ ww);
            }
        int smin = min(min(s00, s01), min(s10, s11));
        float4 c4 = bnc2[base + co];
        int bit = (((float)(576 - 2 * smin) - c4.x) * c4.y + c4.z >= 0.f);  // smax path dropped (monotone, exact)
        word |= (u32)bit << co;
    }
    ((u8*)out2)[idx * 8 + g] = (u8)word;        // little-endian u64 bytes
}

// ---------- K3: fc1 + bn3 + sign -> packed [B,32] ----------
// NB 8->16: 1024 blocks (128 btiles x 8 otiles), 16 independent popc chains
// per thread (2x ILP), weight re-traffic from L2 halved (256->128 passes).

#define NB 16

__global__ __launch_bounds__(256) void k_fc1(
    const u64* __restrict__ act, const u64* __restrict__ wp,
    const float* __restrict__ g, const float* __restrict__ bt,
    const float* __restrict__ mn, const float* __restrict__ vr,
    u64* __restrict__ out3)
{
    int tid = threadIdx.x;
    int btile = blockIdx.x >> 3;               // 128 tiles of NB batches
    int otile = blockIdx.x & 7;                // 8 tiles of 256 outputs
    int b0 = btile * NB;
    int o = otile * 256 + tid;
    const u64* ab = act + b0 * 49;

    int sums[NB];
    #pragma unroll
    for (int i = 0; i < NB; i++) sums[i] = 0;

    for (int p = 0; p < 49; p++) {
        u64 w = wp[p * 2048 + o];
        #pragma unroll
        for (int bb = 0; bb < NB; bb++)
            sums[bb] += __popcll(ab[bb * 49 + p] ^ w);   // ab idx uniform -> s_load
    }

    float iv = g[o] / sqrtf(vr[o] + EPS);
    float m = mn[o], be = bt[o];
    #pragma unroll
    for (int bb = 0; bb < NB; bb++) {
        float y = ((float)(3136 - 2 * sums[bb]) - m) * iv + be;
        u64 ball = __ballot(y >= 0.f);
        if ((tid & 63) == 0) out3[(b0 + bb) * 32 + (o >> 6)] = ball;
    }
}

// ---------- K4: fc2 + scale (unchanged, proven) ----------

__global__ void k_fc2(const u64* __restrict__ act, const u64* __restrict__ w2,
                      const float* __restrict__ scale, float* __restrict__ out)
{
    int idx = blockIdx.x * 256 + threadIdx.x;  // b*16 + o (o<10 active)
    if (idx >= 2048 * 16) return;
    int b = idx >> 4, o = idx & 15;
    if (o >= 10) return;
    int s = 0;
    #pragma unroll
    for (int k = 0; k < 32; k++)
        s += __popcll(act[b * 32 + k] ^ w2[o * 32 + k]);
    out[b * 10 + o] = scale[0] * (float)(2048 - 2 * s);
}

// ======================= launch =======================

extern "C" void kernel_launch(void* const* d_in, const int* in_sizes, int n_in,
                              void* d_out, int out_size, void* d_ws, size_t ws_size,
                              hipStream_t stream) {
    const float* x        = (const float*)d_in[0];
    const float* conv1_w  = (const float*)d_in[1];
    const float* bn1_g    = (const float*)d_in[2];
    const float* bn1_b    = (const float*)d_in[3];
    const float* bn1_m    = (const float*)d_in[4];
    const float* bn1_v    = (const float*)d_in[5];
    const float* conv2_w  = (const float*)d_in[6];
    const float* bn2_g    = (const float*)d_in[7];
    const float* bn2_b    = (const float*)d_in[8];
    const float* bn2_m    = (const float*)d_in[9];
    const float* bn2_v    = (const float*)d_in[10];
    const float* fc1_w    = (const float*)d_in[11];
    const float* bn3_g    = (const float*)d_in[12];
    const float* bn3_b    = (const float*)d_in[13];
    const float* bn3_m    = (const float*)d_in[14];
    const float* bn3_v    = (const float*)d_in[15];
    const float* fc2_w    = (const float*)d_in[16];
    const float* scale    = (const float*)d_in[17];
    float* out = (float*)d_out;

    char* ws = (char*)d_ws;
    v2f*    s1d  = (v2f*)   (ws + 0);          //   4608 B (ends 4608)
    u64*    w2p  = (u64*)   (ws + 4608);       //   4608 B (ends 9216)
    float4* bnc1 = (float4*)(ws + 9216);       //   1024 B (ends 10240)
    float4* bnc2 = (float4*)(ws + 10240);      //   1024 B (ends 11264)
    u64*    w2pk = (u64*)   (ws + 11264);      //   2560 B (ends 13824)
    u64*    wp   = (u64*)   (ws + 16384);      // 802816 B (ends 819200)
    u64*    out1 = (u64*)   (ws + 819200);     // 3211264 B (ends 4030464)
    u64*    out2 = (u64*)   (ws + 4030464);    // 802816 B (ends 4833280)
    u64*    out3 = (u64*)   (ws + 4833280);    // 524288 B (ends 5357568)

    // repack + prep role blocks first (start the HBM streams), conv1 blocks follow
    hipLaunchKernelGGL(k_conv1r, dim3(2048 + 7 + 6272), dim3(256), 0, stream,
                       x, conv1_w, conv2_w, fc2_w,
                       bn1_g, bn1_b, bn1_m, bn1_v,
                       bn2_g, bn2_b, bn2_m, bn2_v,
                       s1d, w2p, w2pk, bnc1, bnc2,
                       out1, fc1_w, wp);
    hipLaunchKernelGGL(k_conv2, dim3(392, 8), dim3(256), 0, stream,
                       out1, w2p, bnc2, out2);
    hipLaunchKernelGGL(k_fc1, dim3(1024), dim3(256), 0, stream,
                       out2, wp, bn3_g, bn3_b, bn3_m, bn3_v, out3);
    hipLaunchKernelGGL(k_fc2, dim3(128), dim3(256), 0, stream,
                       out3, w2pk, scale, out);
}